// Round 19
// baseline (47.909 us; speedup 1.0000x reference)
//
#include <hip/hip_runtime.h>
#include <hip/hip_bf16.h>
#include <math.h>

typedef short short8 __attribute__((ext_vector_type(8)));
typedef float f32x4 __attribute__((ext_vector_type(4)));

#define NQ 32
#define NDOCS 8
#define QLEN 32
#define DLEN 200
#define DIM 128
#define MD 256            // total docs
#define ROWB 256          // LDS row stride bytes (128 bf16)
#define SREP 4            // DIAGNOSTIC: repeat stage+Bq phase (idempotent)

__device__ __forceinline__ short f2bf(float x) {
    union { float f; unsigned u; } v; v.f = x;
    unsigned r = v.u + 0x7FFFu + ((v.u >> 16) & 1u);  // RNE
    return (short)(r >> 16);
}

__device__ __forceinline__ short8 cvt8(float4 f0, float4 f1) {
    short8 o;
    o[0] = f2bf(f0.x); o[1] = f2bf(f0.y); o[2] = f2bf(f0.z); o[3] = f2bf(f0.w);
    o[4] = f2bf(f1.x); o[5] = f2bf(f1.y); o[6] = f2bf(f1.z); o[7] = f2bf(f1.w);
    return o;
}

// chunk c (8 bf16): row=c>>4, kc=c&15; XOR-swizzled LDS write (verified R3..R16)
__device__ __forceinline__ void writeChunk(char* lds, int c, float4 f0, float4 f1) {
    int row = c >> 4, kc = c & 15;
    int byte = row * ROWB + ((kc * 16) ^ ((row & 7) << 4));
    *reinterpret_cast<short8*>(&lds[byte]) = cvt8(f0, f1);
}

// R15 structure; stage+Bq phase repeated SREP times (measurement round).
// grid = 1024: b = qo*256 + m. 256 thr / 4 waves. Wave wid: n = qo*8 + wid*2 + {0,1}.
__global__ __launch_bounds__(256, 2) void colbert_scores(const float* __restrict__ hq,
                                                         const float* __restrict__ hd,
                                                         float* __restrict__ out) {
    __shared__ char lds[208 * ROWB];   // 53248 B (rows 200..207 junk; masked)
    const int tid = threadIdx.x;
    const int b = blockIdx.x;
    const int m = b & 255, qo = b >> 8;
    const int wid = tid >> 6, lane = tid & 63;
    const int lg = lane >> 4, lr = lane & 15;
    const int n0 = qo * 8 + wid * 2;

    const float4* src4 = reinterpret_cast<const float4*>(hd + (size_t)m * (DLEN * DIM));
    short8 Bq[2][2][4];

    // DIAGNOSTIC: repeat the ENTIRE stage + Bq phase. Writes are idempotent
    // (same data to same addresses); Bq reloads produce identical registers.
    // Memory clobber between reps forces real loads/writes each pass.
    #pragma unroll 1
    for (int rep = 0; rep < SREP; ++rep) {
        asm volatile("" ::: "memory");
        // ---- stage doc m: fp32 -> bf16 -> swizzled LDS (3200 chunks) ----
        #pragma unroll
        for (int i = 0; i < 12; ++i) {
            int c = tid + i * 256;
            float4 f0 = src4[c * 2], f1 = src4[c * 2 + 1];
            writeChunk(lds, c, f0, f1);
        }
        if (tid < 128) {
            int c = 3072 + tid;
            float4 f0 = src4[c * 2], f1 = src4[c * 2 + 1];
            writeChunk(lds, c, f0, f1);
        }
        // ---- Bq for 2 questions (fp32 -> bf16 inline) ----
        #pragma unroll
        for (int nn = 0; nn < 2; ++nn)
            #pragma unroll
            for (int qt = 0; qt < 2; ++qt)
                #pragma unroll
                for (int s = 0; s < 4; ++s) {
                    const float4* p = reinterpret_cast<const float4*>(
                        hq + (size_t)((n0 + nn) * QLEN + qt * 16 + lr) * DIM + s * 32 + lg * 8);
                    Bq[nn][qt][s] = cvt8(p[0], p[1]);
                }
    }

    __syncthreads();

    int va[4];
    #pragma unroll
    for (int s = 0; s < 4; ++s)
        va[s] = lr * ROWB + ((s * 64 + lg * 16) ^ ((lr & 7) << 4));

    float qmax[2][2];
    #pragma unroll
    for (int nn = 0; nn < 2; ++nn)
        #pragma unroll
        for (int qt = 0; qt < 2; ++qt) qmax[nn][qt] = -INFINITY;

#define STEP(DT, MASKED)                                                          \
    {                                                                             \
        f32x4 a00 = {0,0,0,0}, a01 = {0,0,0,0}, a10 = {0,0,0,0}, a11 = {0,0,0,0}; \
        _Pragma("unroll")                                                         \
        for (int s = 0; s < 4; ++s) {                                             \
            short8 A_ = *reinterpret_cast<const short8*>(&lds[va[s] + (DT) * 4096]); \
            a00 = __builtin_amdgcn_mfma_f32_16x16x32_bf16(A_, Bq[0][0][s], a00, 0, 0, 0); \
            a01 = __builtin_amdgcn_mfma_f32_16x16x32_bf16(A_, Bq[0][1][s], a01, 0, 0, 0); \
            a10 = __builtin_amdgcn_mfma_f32_16x16x32_bf16(A_, Bq[1][0][s], a10, 0, 0, 0); \
            a11 = __builtin_amdgcn_mfma_f32_16x16x32_bf16(A_, Bq[1][1][s], a11, 0, 0, 0); \
        }                                                                         \
        if (!(MASKED) || lg < 2) {                                                \
            qmax[0][0] = fmaxf(qmax[0][0], fmaxf(fmaxf(a00[0], a00[1]), fmaxf(a00[2], a00[3]))); \
            qmax[0][1] = fmaxf(qmax[0][1], fmaxf(fmaxf(a01[0], a01[1]), fmaxf(a01[2], a01[3]))); \
            qmax[1][0] = fmaxf(qmax[1][0], fmaxf(fmaxf(a10[0], a10[1]), fmaxf(a10[2], a10[3]))); \
            qmax[1][1] = fmaxf(qmax[1][1], fmaxf(fmaxf(a11[0], a11[1]), fmaxf(a11[2], a11[3]))); \
        }                                                                         \
    }

    #pragma unroll
    for (int dt = 0; dt < 12; ++dt) STEP(dt, false);
    STEP(12, true);   // rows 192..199 valid only for lg<2 (200..207 junk, masked)
#undef STEP

    // max over d: combine the 4 lg groups (lanes ^16, ^32)
    #pragma unroll
    for (int off = 16; off <= 32; off <<= 1)
        #pragma unroll
        for (int nn = 0; nn < 2; ++nn)
            #pragma unroll
            for (int qt = 0; qt < 2; ++qt)
                qmax[nn][qt] = fmaxf(qmax[nn][qt], __shfl_xor(qmax[nn][qt], off, 64));

    // mean over q-tokens: lane lr holds tokens lr and 16+lr; sum across the 16 lr lanes
    float s0 = qmax[0][0] + qmax[0][1];
    float s1 = qmax[1][0] + qmax[1][1];
    #pragma unroll
    for (int off = 1; off <= 8; off <<= 1) {
        s0 += __shfl_xor(s0, off, 64);
        s1 += __shfl_xor(s1, off, 64);
    }
    if (lane == 0) {
        out[(size_t)n0 * MD + m] = s0 * (1.0f / 32.0f);
        out[(size_t)(n0 + 1) * MD + m] = s1 * (1.0f / 32.0f);
    }
}

// loss = mean_n( logsumexp(row_n) - row_n[8n] )
__global__ __launch_bounds__(256) void colbert_loss(const float* __restrict__ scores,
                                                    float* __restrict__ loss_out) {
    __shared__ float terms[NQ];
    const int tid = threadIdx.x;
    const int wid = tid >> 6, lane = tid & 63;
    for (int n = wid; n < NQ; n += 4) {
        const float* row = scores + n * MD;
        float v0 = row[lane], v1 = row[64 + lane], v2 = row[128 + lane], v3 = row[192 + lane];
        float mx = fmaxf(fmaxf(v0, v1), fmaxf(v2, v3));
        #pragma unroll
        for (int off = 1; off < 64; off <<= 1) mx = fmaxf(mx, __shfl_xor(mx, off, 64));
        float s = expf(v0 - mx) + expf(v1 - mx) + expf(v2 - mx) + expf(v3 - mx);
        #pragma unroll
        for (int off = 1; off < 64; off <<= 1) s += __shfl_xor(s, off, 64);
        if (lane == 0) terms[n] = (mx + logf(s)) - row[n * NDOCS];
    }
    __syncthreads();
    if (tid == 0) {
        float acc = 0.f;
        #pragma unroll
        for (int n = 0; n < NQ; ++n) acc += terms[n];
        loss_out[0] = acc * (1.0f / NQ);
    }
}

extern "C" void kernel_launch(void* const* d_in, const int* in_sizes, int n_in,
                              void* d_out, int out_size, void* d_ws, size_t ws_size,
                              hipStream_t stream) {
    const float* hq = (const float*)d_in[0];   // [32][32][128] f32
    const float* hd = (const float*)d_in[1];   // [256][200][128] f32
    float* out = (float*)d_out;                // 8192 scores + 1 loss

    colbert_scores<<<1024, 256, 0, stream>>>(hq, hd, out);
    colbert_loss<<<1, 256, 0, stream>>>(out, out + NQ * MD);
}

// Round 20
// 38.258 us; speedup vs baseline: 1.2523x; 1.2523x over previous
//
#include <hip/hip_runtime.h>
#include <hip/hip_bf16.h>
#include <math.h>

typedef short short8 __attribute__((ext_vector_type(8)));
typedef float f32x4 __attribute__((ext_vector_type(4)));

#define NQ 32
#define NDOCS 8
#define QLEN 32
#define DLEN 200
#define DIM 128
#define MD 256            // total docs
#define ROWB 256          // LDS row stride bytes (128 bf16)

__device__ __forceinline__ short f2bf(float x) {
    union { float f; unsigned u; } v; v.f = x;
    unsigned r = v.u + 0x7FFFu + ((v.u >> 16) & 1u);  // RNE
    return (short)(r >> 16);
}

__device__ __forceinline__ short8 cvt8(float4 f0, float4 f1) {
    short8 o;
    o[0] = f2bf(f0.x); o[1] = f2bf(f0.y); o[2] = f2bf(f0.z); o[3] = f2bf(f0.w);
    o[4] = f2bf(f1.x); o[5] = f2bf(f1.y); o[6] = f2bf(f1.z); o[7] = f2bf(f1.w);
    return o;
}

// chunk c (8 bf16): row=c>>4, kc=c&15; XOR-swizzled LDS write. Swizzle depends
// only on row&7, and both half-buffers start at rows == 0 mod 16, so local-row
// formulas are identical for either half.
__device__ __forceinline__ void writeChunk(char* lds, int c, float4 f0, float4 f1) {
    int row = c >> 4, kc = c & 15;
    int byte = row * ROWB + ((kc * 16) ^ ((row & 7) << 4));
    *reinterpret_cast<short8*>(&lds[byte]) = cvt8(f0, f1);
}

// R15 structure + HALF-DOC staging: LDS 28672 B -> 5 blocks/CU -> entire
// 1024-block grid co-resident (no serial generations; 20 waves/CU latency cover).
// grid = 1024: b = qo*256 + m (b%8 = m%8 -> all 4 blocks of doc m on one XCD).
// Block: 256 thr / 4 waves. Wave wid: questions n = qo*8 + wid*2 + {0,1}.
// Phase 1: stage rows 0..111, compute tiles 0..6.
// Phase 2: restage rows 112..207 (200..207 zeroed) into the SAME buffer,
//          compute tiles 7..12 (local 0..5; local 5 masked lg<2).
// C = mfma(A=hd_frag, B=hq_frag): lane holds C[d = dt*16 + lg*4 + r][q = qt*16 + lr].
__global__ __launch_bounds__(256, 2) void colbert_scores(const float* __restrict__ hq,
                                                         const float* __restrict__ hd,
                                                         float* __restrict__ out) {
    __shared__ char lds[112 * ROWB];   // 28672 B
    const int tid = threadIdx.x;
    const int b = blockIdx.x;
    const int m = b & 255, qo = b >> 8;
    const int wid = tid >> 6, lane = tid & 63;
    const int lg = lane >> 4, lr = lane & 15;
    const int n0 = qo * 8 + wid * 2;

    const float4* src4 = reinterpret_cast<const float4*>(hd + (size_t)m * (DLEN * DIM));

    // ---- stage A: rows 0..111 = chunks 0..1791 (7 sweeps) ----
    #pragma unroll
    for (int i = 0; i < 7; ++i) {
        int c = tid + i * 256;
        float4 f0 = src4[c * 2], f1 = src4[c * 2 + 1];
        writeChunk(lds, c, f0, f1);
    }

    // ---- Bq for 2 questions (fp32 -> bf16 inline), overlapped with stage A ----
    short8 Bq[2][2][4];
    #pragma unroll
    for (int nn = 0; nn < 2; ++nn)
        #pragma unroll
        for (int qt = 0; qt < 2; ++qt)
            #pragma unroll
            for (int s = 0; s < 4; ++s) {
                const float4* p = reinterpret_cast<const float4*>(
                    hq + (size_t)((n0 + nn) * QLEN + qt * 16 + lr) * DIM + s * 32 + lg * 8);
                Bq[nn][qt][s] = cvt8(p[0], p[1]);
            }

    __syncthreads();

    int va[4];
    #pragma unroll
    for (int s = 0; s < 4; ++s)
        va[s] = lr * ROWB + ((s * 64 + lg * 16) ^ ((lr & 7) << 4));

    float qmax[2][2];
    #pragma unroll
    for (int nn = 0; nn < 2; ++nn)
        #pragma unroll
        for (int qt = 0; qt < 2; ++qt) qmax[nn][qt] = -INFINITY;

#define STEP(DT, MASKED)                                                          \
    {                                                                             \
        f32x4 a00 = {0,0,0,0}, a01 = {0,0,0,0}, a10 = {0,0,0,0}, a11 = {0,0,0,0}; \
        _Pragma("unroll")                                                         \
        for (int s = 0; s < 4; ++s) {                                             \
            short8 A_ = *reinterpret_cast<const short8*>(&lds[va[s] + (DT) * 4096]); \
            a00 = __builtin_amdgcn_mfma_f32_16x16x32_bf16(A_, Bq[0][0][s], a00, 0, 0, 0); \
            a01 = __builtin_amdgcn_mfma_f32_16x16x32_bf16(A_, Bq[0][1][s], a01, 0, 0, 0); \
            a10 = __builtin_amdgcn_mfma_f32_16x16x32_bf16(A_, Bq[1][0][s], a10, 0, 0, 0); \
            a11 = __builtin_amdgcn_mfma_f32_16x16x32_bf16(A_, Bq[1][1][s], a11, 0, 0, 0); \
        }                                                                         \
        if (!(MASKED) || lg < 2) {                                                \
            qmax[0][0] = fmaxf(qmax[0][0], fmaxf(fmaxf(a00[0], a00[1]), fmaxf(a00[2], a00[3]))); \
            qmax[0][1] = fmaxf(qmax[0][1], fmaxf(fmaxf(a01[0], a01[1]), fmaxf(a01[2], a01[3]))); \
            qmax[1][0] = fmaxf(qmax[1][0], fmaxf(fmaxf(a10[0], a10[1]), fmaxf(a10[2], a10[3]))); \
            qmax[1][1] = fmaxf(qmax[1][1], fmaxf(fmaxf(a11[0], a11[1]), fmaxf(a11[2], a11[3]))); \
        }                                                                         \
    }

    // ---- compute phase 1: tiles 0..6 (rows 0..111) ----
    #pragma unroll
    for (int dt = 0; dt < 7; ++dt) STEP(dt, false);

    __syncthreads();   // all waves done reading buffer before restage

    // ---- stage B: local rows 0..95 = global rows 112..207 (1536 chunks, 6 sweeps);
    //      global rows >= 200 (c >= 1408) are zero pad ----
    #pragma unroll
    for (int i = 0; i < 6; ++i) {
        int c = tid + i * 256;             // local chunk id
        float4 f0 = {0.f, 0.f, 0.f, 0.f}, f1 = {0.f, 0.f, 0.f, 0.f};
        if (c < 1408) {                    // global row = 112 + (c>>4) < 200
            f0 = src4[(1792 + c) * 2];
            f1 = src4[(1792 + c) * 2 + 1];
        }
        writeChunk(lds, c, f0, f1);
    }

    __syncthreads();

    // ---- compute phase 2: tiles 7..12 = local 0..5 (local 5: rows 192..199 valid
    //      only for lg<2; 200..207 are zero pad) ----
    #pragma unroll
    for (int dtl = 0; dtl < 5; ++dtl) STEP(dtl, false);
    STEP(5, true);
#undef STEP

    // max over d: combine the 4 lg groups (lanes ^16, ^32)
    #pragma unroll
    for (int off = 16; off <= 32; off <<= 1)
        #pragma unroll
        for (int nn = 0; nn < 2; ++nn)
            #pragma unroll
            for (int qt = 0; qt < 2; ++qt)
                qmax[nn][qt] = fmaxf(qmax[nn][qt], __shfl_xor(qmax[nn][qt], off, 64));

    // mean over q-tokens: lane lr holds tokens lr and 16+lr; sum across the 16 lr lanes
    float s0 = qmax[0][0] + qmax[0][1];
    float s1 = qmax[1][0] + qmax[1][1];
    #pragma unroll
    for (int off = 1; off <= 8; off <<= 1) {
        s0 += __shfl_xor(s0, off, 64);
        s1 += __shfl_xor(s1, off, 64);
    }
    if (lane == 0) {
        out[(size_t)n0 * MD + m] = s0 * (1.0f / 32.0f);
        out[(size_t)(n0 + 1) * MD + m] = s1 * (1.0f / 32.0f);
    }
}

// loss = mean_n( logsumexp(row_n) - row_n[8n] )
__global__ __launch_bounds__(256) void colbert_loss(const float* __restrict__ scores,
                                                    float* __restrict__ loss_out) {
    __shared__ float terms[NQ];
    const int tid = threadIdx.x;
    const int wid = tid >> 6, lane = tid & 63;
    for (int n = wid; n < NQ; n += 4) {
        const float* row = scores + n * MD;
        float v0 = row[lane], v1 = row[64 + lane], v2 = row[128 + lane], v3 = row[192 + lane];
        float mx = fmaxf(fmaxf(v0, v1), fmaxf(v2, v3));
        #pragma unroll
        for (int off = 1; off < 64; off <<= 1) mx = fmaxf(mx, __shfl_xor(mx, off, 64));
        float s = expf(v0 - mx) + expf(v1 - mx) + expf(v2 - mx) + expf(v3 - mx);
        #pragma unroll
        for (int off = 1; off < 64; off <<= 1) s += __shfl_xor(s, off, 64);
        if (lane == 0) terms[n] = (mx + logf(s)) - row[n * NDOCS];
    }
    __syncthreads();
    if (tid == 0) {
        float acc = 0.f;
        #pragma unroll
        for (int n = 0; n < NQ; ++n) acc += terms[n];
        loss_out[0] = acc * (1.0f / NQ);
    }
}

extern "C" void kernel_launch(void* const* d_in, const int* in_sizes, int n_in,
                              void* d_out, int out_size, void* d_ws, size_t ws_size,
                              hipStream_t stream) {
    const float* hq = (const float*)d_in[0];   // [32][32][128] f32
    const float* hd = (const float*)d_in[1];   // [256][200][128] f32
    float* out = (float*)d_out;                // 8192 scores + 1 loss

    colbert_scores<<<1024, 256, 0, stream>>>(hq, hd, out);
    colbert_loss<<<1, 256, 0, stream>>>(out, out + NQ * MD);
}